// Round 1
// baseline (81.608 us; speedup 1.0000x reference)
//
#include <hip/hip_runtime.h>

#define DZ 512
#define DT 66048
#define SV_JITTER 1e-4f

typedef __attribute__((ext_vector_type(8))) short bf8;
typedef __attribute__((ext_vector_type(4))) float f4;

__device__ __forceinline__ short f2bf(float f) {
  unsigned u = __builtin_bit_cast(unsigned, f);
  return (short)((u + 0x7FFFu + ((u >> 16) & 1u)) >> 16);
}

__device__ __forceinline__ bf8 cvt8(float4 a, float4 b) {
  bf8 r = { f2bf(a.x), f2bf(a.y), f2bf(a.z), f2bf(a.w),
            f2bf(b.x), f2bf(b.y), f2bf(b.z), f2bf(b.w) };
  return r;
}

// Grid: 1032 blocks (64 output cols each) x 256 threads (4 waves, 16 cols/wave).
// acc layout per mfma_f32_16x16x32_bf16: col = lane&15, row = 4*(lane>>4)+reg.
__global__ __launch_bounds__(256)
void sv_kernel(const float* __restrict__ m, const float* __restrict__ Lz,
               const float* __restrict__ Ly, const float* __restrict__ Lyz,
               const float* __restrict__ eps, float* __restrict__ out) {
  // eps tile: 128 samples x 32 k, bf16, row stride 56 shorts (112B: 16B-aligned,
  // bank starts 28*s mod 32 -> 8 lanes cover all 32 banks -> 2-way = free)
  __shared__ short Alds[128 * 56];

  const int b = blockIdx.x;
  const int cbase = b * 64;
  const int tid = threadIdx.x;
  const int wave = tid >> 6;
  const int lane = tid & 63;
  const int lcol = lane & 15;
  const int q = lane >> 4;
  const int c0 = cbase + wave * 16;       // this wave's 16 output columns
  const bool is_z = (cbase < DZ);
  // z tiles: tril => only k <= max col needed. y tiles: 16 K-steps + 2 diag steps.
  const int kkmax = is_z ? (2 * b + 2) : 18;

  f4 acc[8];
  #pragma unroll
  for (int i2 = 0; i2 < 8; ++i2) acc[i2] = f4{0.f, 0.f, 0.f, 0.f};

  // cooperative staging assignment: thread t -> sample s = t&127, k-half (t>>7)*16
  const int ss = tid & 127;
  const int koff = (tid >> 7) * 16;

  for (int kk = 0; kk < kkmax; ++kk) {
    // K-source columns in eps: main loop walks eps_z (0..511);
    // diag steps (kk>=16) walk this block's OWN eps_y columns (== cbase..cbase+63)
    const int ksrc = (kk < 16) ? kk * 32 : cbase + (kk - 16) * 32;

    __syncthreads();  // protect LDS reads of previous iteration
    {
      const float4* s4 = (const float4*)(eps + (size_t)ss * DT + ksrc + koff);
      float4 a = s4[0], b4 = s4[1], c4 = s4[2], d4 = s4[3];
      short* dst = &Alds[ss * 56 + koff];
      *(bf8*)dst = cvt8(a, b4);
      *(bf8*)(dst + 8) = cvt8(c4, d4);
    }
    __syncthreads();

    bf8 bfrag;
    bool active;
    if (kk < 16) {
      const int k0 = kk * 32;
      if (!is_z) {
        active = true;
        // B[k][c] = Lyz[c_global - DZ][k]; lane reads 8 contiguous k (32B fp32)
        const float4* r4 =
            (const float4*)(Lyz + (size_t)(c0 - DZ + lcol) * DZ + k0 + 8 * q);
        bfrag = cvt8(r4[0], r4[1]);
      } else {
        active = (k0 <= c0 + 15);  // wave-uniform tril skip
        if (active) {
          const int i = c0 + lcol;  // output column (< 512) = row of Lz
          const float4* r4 = (const float4*)(Lz + (size_t)i * DZ + k0 + 8 * q);
          float4 x = r4[0], y = r4[1];
          float v[8] = {x.x, x.y, x.z, x.w, y.x, y.y, y.z, y.w};
          #pragma unroll
          for (int t = 0; t < 8; ++t) {
            int k = k0 + 8 * q + t;
            float val = (k < i) ? v[t] : ((k == i) ? v[t] + SV_JITTER : 0.f);
            bfrag[t] = f2bf(val);
          }
        }
      }
    } else {
      // block-diag einsum step h for waves {2h, 2h+1}
      const int h = kk - 16;
      active = ((wave >> 1) == h);
      if (active) {
        const int n = (c0 - DZ) >> 5;            // y-block index
        const int cl = ((c0 - DZ) & 31) + lcol;  // row i of Ly block = out col
        const float4* r4 =
            (const float4*)(Ly + ((size_t)n * 32 + cl) * 32 + 8 * q);
        float4 x = r4[0], y = r4[1];
        float v[8] = {x.x, x.y, x.z, x.w, y.x, y.y, y.z, y.w};
        #pragma unroll
        for (int t = 0; t < 8; ++t) {
          int j = 8 * q + t;
          float val = (j < cl) ? v[t] : ((j == cl) ? v[t] + SV_JITTER : 0.f);
          bfrag[t] = f2bf(val);
        }
      }
    }

    if (active) {
      #pragma unroll
      for (int mi = 0; mi < 8; ++mi) {
        // A[row=16*mi+lcol][k=8*q+t] from staged LDS tile
        const bf8 af = *(const bf8*)(&Alds[(16 * mi + lcol) * 56 + 8 * q]);
        acc[mi] = __builtin_amdgcn_mfma_f32_16x16x32_bf16(af, bfrag, acc[mi], 0, 0, 0);
      }
    }
  }

  const float mval = m[c0 + lcol];
  #pragma unroll
  for (int mi = 0; mi < 8; ++mi) {
    #pragma unroll
    for (int r = 0; r < 4; ++r) {
      const int s = 16 * mi + 4 * q + r;
      out[(size_t)s * DT + c0 + lcol] = acc[mi][r] + mval;
    }
  }
}

extern "C" void kernel_launch(void* const* d_in, const int* in_sizes, int n_in,
                              void* d_out, int out_size, void* d_ws, size_t ws_size,
                              hipStream_t stream) {
  const float* m   = (const float*)d_in[0];
  const float* Lz  = (const float*)d_in[1];
  const float* Ly  = (const float*)d_in[2];
  const float* Lyz = (const float*)d_in[3];
  const float* eps = (const float*)d_in[4];
  float* out = (float*)d_out;
  sv_kernel<<<dim3(66048 / 64), dim3(256), 0, stream>>>(m, Lz, Ly, Lyz, eps, out);
}

// Round 2
// 74.993 us; speedup vs baseline: 1.0882x; 1.0882x over previous
//
#include <hip/hip_runtime.h>

#define DZ 512
#define DT 66048
#define SV_JITTER 1e-4f
#define BIGD 0x3FFFFFFF

typedef __attribute__((ext_vector_type(8))) short bf8;
typedef __attribute__((ext_vector_type(4))) float f4;

__device__ __forceinline__ short f2bf(float f) {
  unsigned u = __builtin_bit_cast(unsigned, f);
  return (short)((u + 0x7FFFu + ((u >> 16) & 1u)) >> 16);
}

__device__ __forceinline__ bf8 cvt8(float4 a, float4 b) {
  bf8 r = { f2bf(a.x), f2bf(a.y), f2bf(a.z), f2bf(a.w),
            f2bf(b.x), f2bf(b.y), f2bf(b.z), f2bf(b.w) };
  return r;
}

// unified tril/jitter cvt: element t has k-index kbase+t; diag==BIGD -> plain copy
__device__ __forceinline__ bf8 cvt8_tril(float4 x, float4 y, int kbase, int diag) {
  float v[8] = {x.x, x.y, x.z, x.w, y.x, y.y, y.z, y.w};
  bf8 r;
  #pragma unroll
  for (int t = 0; t < 8; ++t) {
    int k = kbase + t;
    float val = (k < diag) ? v[t] : ((k == diag) ? v[t] + SV_JITTER : 0.f);
    r[t] = f2bf(val);
  }
  return r;
}

// B-operand source for K-step kk. Returns active?, pointer (2 consecutive float4),
// and tril metadata (diag index within kbase+t numbering).
__device__ __forceinline__ bool b_src(int kk, bool is_z, int cbase, int c0,
                                      int lcol, int q, int wave,
                                      const float* __restrict__ Lz,
                                      const float* __restrict__ Ly,
                                      const float* __restrict__ Lyz,
                                      const float4*& p, int& diag, int& kbase) {
  if (kk < 16) {
    const int k0 = kk * 32;
    if (!is_z) {
      p = (const float4*)(Lyz + (size_t)(c0 - DZ + lcol) * DZ + k0 + 8 * q);
      diag = BIGD; kbase = 0;
      return true;
    }
    if (k0 > c0 + 15) return false;  // wave-uniform tril skip
    const int i = c0 + lcol;         // output column = row of Lz
    p = (const float4*)(Lz + (size_t)i * DZ + k0 + 8 * q);
    diag = i; kbase = k0 + 8 * q;
    return true;
  }
  // block-diag einsum step h serves waves {2h, 2h+1}
  const int h = kk - 16;
  if ((wave >> 1) != h) return false;
  const int n = (c0 - DZ) >> 5;
  const int cl = ((c0 - DZ) & 31) + lcol;  // row of 32x32 Ly block
  p = (const float4*)(Ly + ((size_t)n * 32 + cl) * 32 + 8 * q);
  diag = cl; kbase = 8 * q;
  return true;
}

// Grid: 1032 blocks (64 output cols) x 256 threads (4 waves, 16 cols/wave).
// Software-pipelined: double-buffered LDS eps tile (1 barrier/iter),
// eps + B prefetched 2 iterations ahead into registers.
__global__ __launch_bounds__(256)
void sv_kernel(const float* __restrict__ m, const float* __restrict__ Lz,
               const float* __restrict__ Ly, const float* __restrict__ Lyz,
               const float* __restrict__ eps, float* __restrict__ out) {
  __shared__ short Alds[2][128 * 56];  // stride 56 shorts = 112B, 16B-aligned

  const int b = blockIdx.x;
  const int cbase = b * 64;
  const int tid = threadIdx.x;
  const int wave = tid >> 6;
  const int lane = tid & 63;
  const int lcol = lane & 15;
  const int q = lane >> 4;
  const int c0 = cbase + wave * 16;
  const bool is_z = (cbase < DZ);
  const int kkmax = is_z ? (2 * b + 2) : 18;

  f4 acc[8];
  #pragma unroll
  for (int i2 = 0; i2 < 8; ++i2) acc[i2] = f4{0.f, 0.f, 0.f, 0.f};

  // staging: thread t -> sample s = t&127, k-half (t>>7)*16
  const int ss = tid & 127;
  const int koff = (tid >> 7) * 16;
  const float* epsrow = eps + (size_t)ss * DT + koff;
  auto ksrc = [&](int kk) { return (kk < 16) ? kk * 32 : cbase + (kk - 16) * 32; };

  // ---- prologue ----
  float4 e0, e1, e2, e3;
  {
    const float4* s4 = (const float4*)(epsrow + ksrc(0));
    e0 = s4[0]; e1 = s4[1]; e2 = s4[2]; e3 = s4[3];
  }
  float4 bx{}, by{}; int bdiag = 0, bkbase = 0;
  bool bact;
  {
    const float4* p; int d, kb;
    bact = b_src(0, is_z, cbase, c0, lcol, q, wave, Lz, Ly, Lyz, p, d, kb);
    if (bact) { bx = p[0]; by = p[1]; bdiag = d; bkbase = kb; }
  }
  {  // stage tile 0 into buffer 0
    short* dst = &Alds[0][ss * 56 + koff];
    *(bf8*)dst = cvt8(e0, e1);
    *(bf8*)(dst + 8) = cvt8(e2, e3);
  }
  if (kkmax > 1) {  // prefetch eps(1)
    const float4* s4 = (const float4*)(epsrow + ksrc(1));
    e0 = s4[0]; e1 = s4[1]; e2 = s4[2]; e3 = s4[3];
  }
  float4 nbx{}, nby{}; int nbdiag = 0, nbkbase = 0;
  bool nbact = false;
  if (kkmax > 1) {  // prefetch B(1)
    const float4* p; int d, kb;
    nbact = b_src(1, is_z, cbase, c0, lcol, q, wave, Lz, Ly, Lyz, p, d, kb);
    if (nbact) { nbx = p[0]; nby = p[1]; nbdiag = d; nbkbase = kb; }
  }
  __syncthreads();

  // ---- main loop: one barrier per iteration ----
  for (int kk = 0; kk < kkmax; ++kk) {
    const int cur = kk & 1;
    if (kk + 1 < kkmax) {  // write eps(kk+1) regs -> other buffer (nobody reads it now)
      short* dst = &Alds[cur ^ 1][ss * 56 + koff];
      *(bf8*)dst = cvt8(e0, e1);
      *(bf8*)(dst + 8) = cvt8(e2, e3);
    }
    if (kk + 2 < kkmax) {  // issue eps(kk+2); full iteration to land
      const float4* s4 = (const float4*)(epsrow + ksrc(kk + 2));
      e0 = s4[0]; e1 = s4[1]; e2 = s4[2]; e3 = s4[3];
    }

    const bool act = bact;
    bf8 bfrag;
    if (act) bfrag = cvt8_tril(bx, by, bkbase, bdiag);
    // rotate B pipeline, then issue B(kk+2)
    bact = nbact; bx = nbx; by = nby; bdiag = nbdiag; bkbase = nbkbase;
    if (kk + 2 < kkmax) {
      const float4* p; int d, kb;
      nbact = b_src(kk + 2, is_z, cbase, c0, lcol, q, wave, Lz, Ly, Lyz, p, d, kb);
      if (nbact) { nbx = p[0]; nby = p[1]; nbdiag = d; nbkbase = kb; }
    } else {
      nbact = false;
    }

    if (act) {
      #pragma unroll
      for (int mi = 0; mi < 8; ++mi) {
        const bf8 af = *(const bf8*)(&Alds[cur][(16 * mi + lcol) * 56 + 8 * q]);
        acc[mi] = __builtin_amdgcn_mfma_f32_16x16x32_bf16(af, bfrag, acc[mi], 0, 0, 0);
      }
    }
    __syncthreads();
  }

  const float mval = m[c0 + lcol];
  #pragma unroll
  for (int mi = 0; mi < 8; ++mi) {
    #pragma unroll
    for (int r = 0; r < 4; ++r) {
      const int s = 16 * mi + 4 * q + r;
      out[(size_t)s * DT + c0 + lcol] = acc[mi][r] + mval;
    }
  }
}

extern "C" void kernel_launch(void* const* d_in, const int* in_sizes, int n_in,
                              void* d_out, int out_size, void* d_ws, size_t ws_size,
                              hipStream_t stream) {
  const float* m   = (const float*)d_in[0];
  const float* Lz  = (const float*)d_in[1];
  const float* Ly  = (const float*)d_in[2];
  const float* Lyz = (const float*)d_in[3];
  const float* eps = (const float*)d_in[4];
  float* out = (float*)d_out;
  sv_kernel<<<dim3(66048 / 64), dim3(256), 0, stream>>>(m, Lz, Ly, Lyz, eps, out);
}